// Round 1
// 400.459 us; speedup vs baseline: 1.0259x; 1.0259x over previous
//
#include <hip/hip_runtime.h>
#include <math.h>

// NoisyTopKRouter: x[65536,1024] fp32 -> gates[65536,8] + aux_loss.
// R4: T4 counted-vmcnt retrofit of R3. R3's per-chunk __syncthreads() made
// the compiler emit s_waitcnt vmcnt(0) before s_barrier, draining the
// in-flight chunk-(c+1) global_load_lds prefetch 16x per block (the known
// ~20%+ barrier-drain stall, guide section 5). Replace with:
//   per-wave s_waitcnt vmcnt(4)  -> only chunk c's own 4 loads drained
//   raw s_barrier                -> all waves' chunk-c data in LDS
//   ds_reads + lgkmcnt(0)        -> this wave's reads of buf b retired
//   raw s_barrier                -> all waves done reading buf b
//   issue chunk c+2 into buf b   -> stays in flight across next barrier
// Staging map, quad-padded LDS (QSTRIDE=260 -> 8-words/bank floor), compute
// map, 4-way k-split combine and fused epilogue are unchanged from R3
// (verified there). Occupancy unchanged: 33,280 B LDS, 4 blocks/CU.

#define N_TOKENS   65536
#define EMBED_DIM  1024
#define NE         8
#define BROWS      64                    // rows per block (= one wave of lanes)
#define CHUNK      64                    // k-cols per chunk
#define NCHUNK     (EMBED_DIM / CHUNK)   // 16
#define QSTRIDE    260                   // floats per 4-row quad (256 + 4 pad)
#define NSLOT      64                    // aux accumulator spreading
#define NOISE_EPS  0.2f

#define AS1(p) (const __attribute__((address_space(1))) void*)(p)
#define AS3(p) (__attribute__((address_space(3))) void*)(p)

__global__ __launch_bounds__(256, 4)
void router_kernel(const float* __restrict__ x,
                   const float* __restrict__ eps,
                   const float* __restrict__ wg,
                   const float* __restrict__ wn,
                   float* __restrict__ gates,
                   float* __restrict__ acc /* NSLOT x 16 floats */) {
    __shared__ float tile[2][16 * QSTRIDE];   // 33280 B; quad q at q*260 floats

    const int t    = threadIdx.x;
    const int lane = t & 63;
    const int w    = __builtin_amdgcn_readfirstlane(t >> 6);   // wave id 0..3
    const long rowbase = (long)blockIdx.x * BROWS;

    // staging map: wave w issues 4 glb_lds, instr i covers quad q=w*4+i
    // (rows 4q..4q+3, cols c*64..+63). lane -> row 4q+(lane>>4), col (lane&15)*4.
    const int srow = lane >> 4;           // 0..3
    const int scol = (lane & 15) * 4;     // 0..60

    // compute map: lane -> row `lane`; float4 base within tile:
    const int tb = (lane >> 2) * QSTRIDE + (lane & 3) * 64 + w * 16;

    float accg[NE], accn[NE];
#pragma unroll
    for (int e = 0; e < NE; ++e) { accg[e] = 0.f; accn[e] = 0.f; }

    // prologue: stage chunk 0 -> buf0, chunk 1 -> buf1 (8 loads in flight/wave)
#pragma unroll
    for (int cc = 0; cc < 2; ++cc)
#pragma unroll
        for (int i = 0; i < 4; ++i) {
            const int q = w * 4 + i;
            const float* gp = x + (rowbase + q * 4 + srow) * (long)EMBED_DIM
                              + cc * CHUNK + scol;
            __builtin_amdgcn_global_load_lds(AS1(gp), AS3(&tile[cc][q * QSTRIDE]),
                                             16, 0, 0);
        }

#pragma unroll 1
    for (int c = 0; c < NCHUNK; ++c) {
        const int b = c & 1;

        // counted wait: chunk c's own 4 loads landed; chunk c+1's 4 stay in
        // flight across the barrier (T4 — never drain vmcnt(0) mid-loop).
        if (c == NCHUNK - 1) asm volatile("s_waitcnt vmcnt(0)" ::: "memory");
        else                 asm volatile("s_waitcnt vmcnt(4)" ::: "memory");
        __builtin_amdgcn_s_barrier();          // all waves' chunk-c data in LDS
        asm volatile("" ::: "memory");         // no load hoisted above barrier

        // wave w consumes k-slice [c*64+16w, +16)
        float4 xv[4];
#pragma unroll
        for (int j = 0; j < 4; ++j)
            xv[j] = *(const float4*)&tile[b][tb + j * 4];
        asm volatile("s_waitcnt lgkmcnt(0)" ::: "memory");  // reads retired
        __builtin_amdgcn_sched_barrier(0);
        __builtin_amdgcn_s_barrier();          // all waves done reading buf b
        asm volatile("" ::: "memory");

        // refill buf b with chunk c+2; lands while we (and others) FMA
        if (c + 2 < NCHUNK) {
#pragma unroll
            for (int i = 0; i < 4; ++i) {
                const int q = w * 4 + i;
                const float* gp = x + (rowbase + q * 4 + srow) * (long)EMBED_DIM
                                  + (c + 2) * CHUNK + scol;
                __builtin_amdgcn_global_load_lds(AS1(gp),
                                                 AS3(&tile[b][q * QSTRIDE]),
                                                 16, 0, 0);
            }
        }

        // weights are wave-uniform -> s_load through the scalar cache
        const float* wgc = wg + ((long)c * CHUNK + w * 16) * NE;
        const float* wnc = wn + ((long)c * CHUNK + w * 16) * NE;
#pragma unroll
        for (int j = 0; j < 4; ++j) {
            const float xa[4] = { xv[j].x, xv[j].y, xv[j].z, xv[j].w };
#pragma unroll
            for (int q = 0; q < 4; ++q) {
                const int k = j * 4 + q;
#pragma unroll
                for (int e = 0; e < NE; ++e) {
                    accg[e] = fmaf(xa[q], wgc[k * NE + e], accg[e]);
                    accn[e] = fmaf(xa[q], wnc[k * NE + e], accn[e]);
                }
            }
        }
    }

    // ---- combine 4-way k-split (reuse tile as scratch: 12 KB < 33 KB) ----
    float* part = (float*)tile;
    if (w != 0) {
#pragma unroll
        for (int e = 0; e < NE; ++e) {
            part[((w - 1) * BROWS + lane) * 16 + e]      = accg[e];
            part[((w - 1) * BROWS + lane) * 16 + NE + e] = accn[e];
        }
    }
    __syncthreads();
    if (w != 0) return;

#pragma unroll
    for (int v = 0; v < 3; ++v)
#pragma unroll
        for (int e = 0; e < NE; ++e) {
            accg[e] += part[(v * BROWS + lane) * 16 + e];
            accn[e] += part[(v * BROWS + lane) * 16 + NE + e];
        }

    // ---- fused epilogue (wave 0, one row per lane) — verified in R1/R2 ----
    const long row = rowbase + lane;
    const float* er = eps + row * NE;
    float4 ev0 = *(const float4*)(er);
    float4 ev1 = *(const float4*)(er + 4);
    float epsv[NE] = { ev0.x, ev0.y, ev0.z, ev0.w, ev1.x, ev1.y, ev1.z, ev1.w };

    float noisy[NE];
#pragma unroll
    for (int e = 0; e < NE; ++e) {
        float r = accn[e];
        float sp = fmaxf(r, 0.f) + log1pf(expf(-fabsf(r)));   // stable softplus
        noisy[e] = accg[e] + (sp + NOISE_EPS) * epsv[e];
    }

    int i1 = 0; float v1 = noisy[0];
#pragma unroll
    for (int e = 1; e < NE; ++e) if (noisy[e] > v1) { v1 = noisy[e]; i1 = e; }
    int i2 = -1; float v2 = -INFINITY;
#pragma unroll
    for (int e = 0; e < NE; ++e) if (e != i1 && noisy[e] > v2) { v2 = noisy[e]; i2 = e; }

    float bb = expf(v2 - v1);
    float g2 = bb / (1.f + bb);
    float g1 = 1.f - g2;

    float* gr = gates + row * NE;
    float ov[NE];
#pragma unroll
    for (int e = 0; e < NE; ++e)
        ov[e] = (e == i1) ? g1 : ((e == i2) ? g2 : 0.f);
    *(float4*)(gr)     = make_float4(ov[0], ov[1], ov[2], ov[3]);
    *(float4*)(gr + 4) = make_float4(ov[4], ov[5], ov[6], ov[7]);

    float mx = accg[0];
#pragma unroll
    for (int e = 1; e < NE; ++e) mx = fmaxf(mx, accg[e]);
    float p[NE]; float s = 0.f;
#pragma unroll
    for (int e = 0; e < NE; ++e) { p[e] = expf(accg[e] - mx); s += p[e]; }
    float inv = 1.f / s;

    float vals[16];
#pragma unroll
    for (int e = 0; e < NE; ++e) {
        vals[e]      = p[e] * inv;
        vals[NE + e] = ((i1 == e) ? 1.f : 0.f) + ((i2 == e && g2 > 0.f) ? 1.f : 0.f);
    }
#pragma unroll
    for (int off = 32; off > 0; off >>= 1)
#pragma unroll
        for (int i = 0; i < 16; ++i)
            vals[i] += __shfl_xor(vals[i], off, 64);

    if (lane == 0) {
        float* slot = acc + (blockIdx.x & (NSLOT - 1)) * 16;
#pragma unroll
        for (int i = 0; i < 16; ++i)
            atomicAdd(&slot[i], vals[i]);
    }
}

__global__ void finalize_kernel(const float* __restrict__ acc,
                                float* __restrict__ out_aux) {
    __shared__ float s[16];
    const int t = threadIdx.x;
    if (t < 16) {
        float v = 0.f;
        for (int j = 0; j < NSLOT; ++j) v += acc[j * 16 + t];
        s[t] = v;
    }
    __syncthreads();
    if (t == 0) {
        const float invn = 1.f / (float)N_TOKENS;
        float aux = 0.f;
#pragma unroll
        for (int e = 0; e < NE; ++e)
            aux += (s[e] * invn) * (s[NE + e] * invn);
        *out_aux = (float)NE * aux;
    }
}

extern "C" void kernel_launch(void* const* d_in, const int* in_sizes, int n_in,
                              void* d_out, int out_size, void* d_ws, size_t ws_size,
                              hipStream_t stream) {
    const float* x   = (const float*)d_in[0];
    const float* eps = (const float*)d_in[1];
    const float* wg  = (const float*)d_in[2];
    const float* wn  = (const float*)d_in[3];
    float* out = (float*)d_out;
    float* acc = (float*)d_ws;

    hipMemsetAsync(d_ws, 0, NSLOT * 16 * sizeof(float), stream);

    router_kernel<<<dim3(N_TOKENS / BROWS), dim3(256), 0, stream>>>(
        x, eps, wg, wn, out, acc);
    finalize_kernel<<<dim3(1), dim3(64), 0, stream>>>(acc, out + (out_size - 1));
}

// Round 2
// 378.856 us; speedup vs baseline: 1.0844x; 1.0570x over previous
//
#include <hip/hip_runtime.h>
#include <math.h>

// NoisyTopKRouter: x[65536,1024] fp32 -> gates[65536,8] + aux_loss.
// R5 = R4 + per-block chunk-phase STAGGER. R4 (counted vmcnt, raw barriers)
// gained 10us -> sync structure is no longer the dominant loss. Theory: the
// device-wide access is a synchronized column comb -- at chunk c every block
// reads 256B-units with index = c (mod 16) (block bases are multiples of
// 256KB so the residue is device-global). That concentrates HBM traffic on a
// structured 1/16 of the 256B address lattice per chunk period and gives one
// 256B touch per 4KB DRAM page -> channel/page imbalance, BW capped ~2-3x
// below the 6.3 TB/s streaming ceiling. Fix: block b starts at chunk b&15 and
// rotates -- at any instant all 16 residue classes are active uniformly.
// Weights stay wave-uniform (chunk id is scalar) -> s_load path untouched.
// Everything else (staging map, QSTRIDE=260 quad padding = 8-words/bank
// floor, 2-buf + counted vmcnt(4) + dual raw barriers, 4-way k-split combine,
// fused epilogue) is unchanged from R4. Only k-sum ORDER per row rotates
// (fp32 rounding perturbation ~1e-6 rel).

#define N_TOKENS   65536
#define EMBED_DIM  1024
#define NE         8
#define BROWS      64                    // rows per block (= one wave of lanes)
#define CHUNK      64                    // k-cols per chunk
#define NCHUNK     (EMBED_DIM / CHUNK)   // 16
#define QSTRIDE    260                   // floats per 4-row quad (256 + 4 pad)
#define NSLOT      64                    // aux accumulator spreading
#define NOISE_EPS  0.2f

#define AS1(p) (const __attribute__((address_space(1))) void*)(p)
#define AS3(p) (__attribute__((address_space(3))) void*)(p)

__global__ __launch_bounds__(256, 4)
void router_kernel(const float* __restrict__ x,
                   const float* __restrict__ eps,
                   const float* __restrict__ wg,
                   const float* __restrict__ wn,
                   float* __restrict__ gates,
                   float* __restrict__ acc /* NSLOT x 16 floats */) {
    __shared__ float tile[2][16 * QSTRIDE];   // 33280 B; quad q at q*260 floats

    const int t    = threadIdx.x;
    const int lane = t & 63;
    const int w    = __builtin_amdgcn_readfirstlane(t >> 6);   // wave id 0..3
    const long rowbase = (long)blockIdx.x * BROWS;
    const int  c0 = blockIdx.x & (NCHUNK - 1);   // per-block chunk phase

    // staging map: wave w issues 4 glb_lds, instr i covers quad q=w*4+i
    // (rows 4q..4q+3, cols ca*64..+63). lane -> row 4q+(lane>>4), col (lane&15)*4.
    const int srow = lane >> 4;           // 0..3
    const int scol = (lane & 15) * 4;     // 0..60

    // compute map: lane -> row `lane`; float4 base within tile:
    const int tb = (lane >> 2) * QSTRIDE + (lane & 3) * 64 + w * 16;

    float accg[NE], accn[NE];
#pragma unroll
    for (int e = 0; e < NE; ++e) { accg[e] = 0.f; accn[e] = 0.f; }

    // prologue: stage logical chunks 0,1 (physical c0, c0+1) -> bufs 0,1
#pragma unroll
    for (int cc = 0; cc < 2; ++cc) {
        const int ca = (c0 + cc) & (NCHUNK - 1);
#pragma unroll
        for (int i = 0; i < 4; ++i) {
            const int q = w * 4 + i;
            const float* gp = x + (rowbase + q * 4 + srow) * (long)EMBED_DIM
                              + ca * CHUNK + scol;
            __builtin_amdgcn_global_load_lds(AS1(gp), AS3(&tile[cc][q * QSTRIDE]),
                                             16, 0, 0);
        }
    }

#pragma unroll 1
    for (int c = 0; c < NCHUNK; ++c) {
        const int b  = c & 1;
        const int ca = (c0 + c) & (NCHUNK - 1);   // physical chunk this iter

        // counted wait: logical chunk c's own 4 loads landed; chunk c+1's 4
        // stay in flight across the barrier (T4 — never drain mid-loop).
        if (c == NCHUNK - 1) asm volatile("s_waitcnt vmcnt(0)" ::: "memory");
        else                 asm volatile("s_waitcnt vmcnt(4)" ::: "memory");
        __builtin_amdgcn_s_barrier();          // all waves' chunk-c data in LDS
        asm volatile("" ::: "memory");         // no load hoisted above barrier

        // wave w consumes k-slice [ca*64+16w, +16)
        float4 xv[4];
#pragma unroll
        for (int j = 0; j < 4; ++j)
            xv[j] = *(const float4*)&tile[b][tb + j * 4];
        asm volatile("s_waitcnt lgkmcnt(0)" ::: "memory");  // reads retired
        __builtin_amdgcn_sched_barrier(0);
        __builtin_amdgcn_s_barrier();          // all waves done reading buf b
        asm volatile("" ::: "memory");

        // refill buf b with logical chunk c+2; lands while we FMA
        if (c + 2 < NCHUNK) {
            const int can = (c0 + c + 2) & (NCHUNK - 1);
#pragma unroll
            for (int i = 0; i < 4; ++i) {
                const int q = w * 4 + i;
                const float* gp = x + (rowbase + q * 4 + srow) * (long)EMBED_DIM
                                  + can * CHUNK + scol;
                __builtin_amdgcn_global_load_lds(AS1(gp),
                                                 AS3(&tile[b][q * QSTRIDE]),
                                                 16, 0, 0);
            }
        }

        // weights are wave-uniform (ca is scalar) -> s_load / scalar K$ path
        const float* wgc = wg + ((long)ca * CHUNK + w * 16) * NE;
        const float* wnc = wn + ((long)ca * CHUNK + w * 16) * NE;
#pragma unroll
        for (int j = 0; j < 4; ++j) {
            const float xa[4] = { xv[j].x, xv[j].y, xv[j].z, xv[j].w };
#pragma unroll
            for (int q = 0; q < 4; ++q) {
                const int k = j * 4 + q;
#pragma unroll
                for (int e = 0; e < NE; ++e) {
                    accg[e] = fmaf(xa[q], wgc[k * NE + e], accg[e]);
                    accn[e] = fmaf(xa[q], wnc[k * NE + e], accn[e]);
                }
            }
        }
    }

    // ---- combine 4-way k-split (reuse tile as scratch: 12 KB < 33 KB) ----
    float* part = (float*)tile;
    if (w != 0) {
#pragma unroll
        for (int e = 0; e < NE; ++e) {
            part[((w - 1) * BROWS + lane) * 16 + e]      = accg[e];
            part[((w - 1) * BROWS + lane) * 16 + NE + e] = accn[e];
        }
    }
    __syncthreads();
    if (w != 0) return;

#pragma unroll
    for (int v = 0; v < 3; ++v)
#pragma unroll
        for (int e = 0; e < NE; ++e) {
            accg[e] += part[(v * BROWS + lane) * 16 + e];
            accn[e] += part[(v * BROWS + lane) * 16 + NE + e];
        }

    // ---- fused epilogue (wave 0, one row per lane) — verified in R1/R2 ----
    const long row = rowbase + lane;
    const float* er = eps + row * NE;
    float4 ev0 = *(const float4*)(er);
    float4 ev1 = *(const float4*)(er + 4);
    float epsv[NE] = { ev0.x, ev0.y, ev0.z, ev0.w, ev1.x, ev1.y, ev1.z, ev1.w };

    float noisy[NE];
#pragma unroll
    for (int e = 0; e < NE; ++e) {
        float r = accn[e];
        float sp = fmaxf(r, 0.f) + log1pf(expf(-fabsf(r)));   // stable softplus
        noisy[e] = accg[e] + (sp + NOISE_EPS) * epsv[e];
    }

    int i1 = 0; float v1 = noisy[0];
#pragma unroll
    for (int e = 1; e < NE; ++e) if (noisy[e] > v1) { v1 = noisy[e]; i1 = e; }
    int i2 = -1; float v2 = -INFINITY;
#pragma unroll
    for (int e = 0; e < NE; ++e) if (e != i1 && noisy[e] > v2) { v2 = noisy[e]; i2 = e; }

    float bb = expf(v2 - v1);
    float g2 = bb / (1.f + bb);
    float g1 = 1.f - g2;

    float* gr = gates + row * NE;
    float ov[NE];
#pragma unroll
    for (int e = 0; e < NE; ++e)
        ov[e] = (e == i1) ? g1 : ((e == i2) ? g2 : 0.f);
    *(float4*)(gr)     = make_float4(ov[0], ov[1], ov[2], ov[3]);
    *(float4*)(gr + 4) = make_float4(ov[4], ov[5], ov[6], ov[7]);

    float mx = accg[0];
#pragma unroll
    for (int e = 1; e < NE; ++e) mx = fmaxf(mx, accg[e]);
    float p[NE]; float s = 0.f;
#pragma unroll
    for (int e = 0; e < NE; ++e) { p[e] = expf(accg[e] - mx); s += p[e]; }
    float inv = 1.f / s;

    float vals[16];
#pragma unroll
    for (int e = 0; e < NE; ++e) {
        vals[e]      = p[e] * inv;
        vals[NE + e] = ((i1 == e) ? 1.f : 0.f) + ((i2 == e && g2 > 0.f) ? 1.f : 0.f);
    }
#pragma unroll
    for (int off = 32; off > 0; off >>= 1)
#pragma unroll
        for (int i = 0; i < 16; ++i)
            vals[i] += __shfl_xor(vals[i], off, 64);

    if (lane == 0) {
        float* slot = acc + (blockIdx.x & (NSLOT - 1)) * 16;
#pragma unroll
        for (int i = 0; i < 16; ++i)
            atomicAdd(&slot[i], vals[i]);
    }
}

__global__ void finalize_kernel(const float* __restrict__ acc,
                                float* __restrict__ out_aux) {
    __shared__ float s[16];
    const int t = threadIdx.x;
    if (t < 16) {
        float v = 0.f;
        for (int j = 0; j < NSLOT; ++j) v += acc[j * 16 + t];
        s[t] = v;
    }
    __syncthreads();
    if (t == 0) {
        const float invn = 1.f / (float)N_TOKENS;
        float aux = 0.f;
#pragma unroll
        for (int e = 0; e < NE; ++e)
            aux += (s[e] * invn) * (s[NE + e] * invn);
        *out_aux = (float)NE * aux;
    }
}

extern "C" void kernel_launch(void* const* d_in, const int* in_sizes, int n_in,
                              void* d_out, int out_size, void* d_ws, size_t ws_size,
                              hipStream_t stream) {
    const float* x   = (const float*)d_in[0];
    const float* eps = (const float*)d_in[1];
    const float* wg  = (const float*)d_in[2];
    const float* wn  = (const float*)d_in[3];
    float* out = (float*)d_out;
    float* acc = (float*)d_ws;

    hipMemsetAsync(d_ws, 0, NSLOT * 16 * sizeof(float), stream);

    router_kernel<<<dim3(N_TOKENS / BROWS), dim3(256), 0, stream>>>(
        x, eps, wg, wn, out, acc);
    finalize_kernel<<<dim3(1), dim3(64), 0, stream>>>(acc, out + (out_size - 1));
}